// Round 1
// baseline (377.838 us; speedup 1.0000x reference)
//
#include <hip/hip_runtime.h>

// DeTPP loss: L=2048, B=64, K=4, C=128, I=512 selected positions per batch.
#define LL 2048
#define BB 64
#define KT 4
#define CC 128
#define II 512
#define NPOS (II * BB)   // 32768

// One block per (i, b) position. 256 threads = 4 waves; wave k owns logits row k.
__global__ __launch_bounds__(256) void detpp_main(
    const float* __restrict__ in_time,     // (L, B)
    const float* __restrict__ in_amount,   // (L, B)
    const int*   __restrict__ in_mcc,      // (L, B)
    const float* __restrict__ out_time,    // (L, B, K)
    const float* __restrict__ out_amount,  // (L, B, K)
    const float* __restrict__ out_logits,  // (L, B, K, C)
    const float* __restrict__ presence,    // (L, B, K)
    const int*   __restrict__ indices,     // (I, B)
    const int*   __restrict__ subset_lengths, // (B,)
    float* __restrict__ partials)          // (NPOS,)
{
    const int blk = blockIdx.x;          // blk = i*B + b
    const int i   = blk >> 6;            // B == 64
    const int b   = blk & 63;
    const int tid = threadIdx.x;

    __shared__ float s_tw[KT + 1], s_aw[KT + 1];
    __shared__ int   s_cw[KT + 1];
    __shared__ float s_ot[KT], s_oa[KT], s_ps[KT];
    __shared__ float s_cost[KT][KT];
    __shared__ int   s_idx, s_valid;

    if (tid == 0) {
        s_idx   = indices[blk];
        s_valid = (i < subset_lengths[b]) ? 1 : 0;
    }
    __syncthreads();

    if (!s_valid) {
        if (tid == 0) partials[blk] = 0.0f;
        return;
    }
    const int idx = s_idx;

    // Small gathers: rolling window over inputs (wraps mod L like jnp.roll),
    // and the K-sized output/presence slices at this position.
    if (tid < KT + 1) {
        int row = idx + tid;
        if (row >= LL) row -= LL;            // jnp.roll wrap
        s_tw[tid] = in_time[row * BB + b];
        s_aw[tid] = in_amount[row * BB + b];
        s_cw[tid] = in_mcc[row * BB + b];
    } else if (tid >= 64 && tid < 64 + KT) {
        const int k = tid - 64;
        const size_t base = ((size_t)idx * BB + b) * KT + k;
        s_ot[k] = out_time[base];
        s_oa[k] = out_amount[base];
        s_ps[k] = presence[base];
    }
    __syncthreads();

    const int wave = tid >> 6;
    const int lane = tid & 63;

    // Wave `wave` handles logits row k=wave: 128 floats, float2 per lane (coalesced).
    const size_t lbase = (((size_t)idx * BB + b) * KT + wave) * CC;
    const float2 v = *reinterpret_cast<const float2*>(out_logits + lbase + lane * 2);

    // logsumexp over C=128 via 64-lane butterfly reduce
    float mx = fmaxf(v.x, v.y);
    #pragma unroll
    for (int m = 32; m >= 1; m >>= 1) mx = fmaxf(mx, __shfl_xor(mx, m));
    float se = __expf(v.x - mx) + __expf(v.y - mx);
    #pragma unroll
    for (int m = 32; m >= 1; m >>= 1) se += __shfl_xor(se, m);
    const float lse = mx + logf(se);

    // Lanes 0..3 of each wave build cost[k=wave][t=lane]
    if (lane < KT) {
        const int t = lane;
        const float ol_true = out_logits[lbase + s_cw[t + 1]];   // L2-hot
        const float ce  = lse - ol_true;                          // -log_softmax at true class
        const float l1t = fabsf(s_ot[wave] - (s_tw[t + 1] - s_tw[0]));
        const float l1a = fabsf(s_oa[wave] - s_aw[t + 1]);
        s_cost[wave][t] = ce + l1t + l1a - s_ps[wave];
    }
    __syncthreads();

    if (tid == 0) {
        float c[KT][KT];
        #pragma unroll
        for (int k = 0; k < KT; k++)
            #pragma unroll
            for (int t = 0; t < KT; t++) c[k][t] = s_cost[k][t];

        // Exact assignment: min over all 24 permutations of K=4
        const signed char P[24][4] = {
            {0,1,2,3},{0,1,3,2},{0,2,1,3},{0,2,3,1},{0,3,1,2},{0,3,2,1},
            {1,0,2,3},{1,0,3,2},{1,2,0,3},{1,2,3,0},{1,3,0,2},{1,3,2,0},
            {2,0,1,3},{2,0,3,1},{2,1,0,3},{2,1,3,0},{2,3,0,1},{2,3,1,0},
            {3,0,1,2},{3,0,2,1},{3,1,0,2},{3,1,2,0},{3,2,0,1},{3,2,1,0}};
        float best = 3.4e38f;
        #pragma unroll
        for (int p = 0; p < 24; p++) {
            const float s = c[0][P[p][0]] + c[1][P[p][1]] +
                            c[2][P[p][2]] + c[3][P[p][3]];
            best = fminf(best, s);
        }

        // leftover: sum_k softplus(presence[k])   (= -log_sigmoid(-x))
        float leftover = 0.0f;
        #pragma unroll
        for (int k = 0; k < KT; k++) {
            const float x = s_ps[k];
            leftover += fmaxf(x, 0.0f) + log1pf(__expf(-fabsf(x)));
        }
        partials[blk] = best + leftover;
    }
}

__global__ __launch_bounds__(1024) void detpp_finish(
    const float* __restrict__ partials,
    const int*   __restrict__ subset_lengths,
    float* __restrict__ out)
{
    const int tid = threadIdx.x;
    float s = 0.0f;
    for (int j = tid; j < NPOS; j += 1024) s += partials[j];
    #pragma unroll
    for (int m = 32; m >= 1; m >>= 1) s += __shfl_xor(s, m);

    __shared__ float red[16];
    const int wave = tid >> 6;
    const int lane = tid & 63;
    if (lane == 0) red[wave] = s;
    __syncthreads();

    if (tid == 0) {
        float tot = 0.0f;
        #pragma unroll
        for (int w = 0; w < 16; w++) tot += red[w];
        int V = 0;
        for (int bb = 0; bb < BB; bb++) V += subset_lengths[bb];
        out[0] = tot / (float)V;
    }
}

extern "C" void kernel_launch(void* const* d_in, const int* in_sizes, int n_in,
                              void* d_out, int out_size, void* d_ws, size_t ws_size,
                              hipStream_t stream) {
    const float* in_time        = (const float*)d_in[0];
    const float* in_amount      = (const float*)d_in[1];
    const int*   in_mcc         = (const int*)  d_in[2];
    const float* out_time       = (const float*)d_in[3];
    const float* out_amount     = (const float*)d_in[4];
    const float* out_logits     = (const float*)d_in[5];
    const float* presence       = (const float*)d_in[6];
    // d_in[7] = lengths (unused; indices/subset_lengths already encode validity)
    const int*   indices        = (const int*)  d_in[8];
    const int*   subset_lengths = (const int*)  d_in[9];

    float* partials = (float*)d_ws;   // NPOS floats = 128 KB

    detpp_main<<<NPOS, 256, 0, stream>>>(
        in_time, in_amount, in_mcc, out_time, out_amount, out_logits,
        presence, indices, subset_lengths, partials);

    detpp_finish<<<1, 1024, 0, stream>>>(partials, subset_lengths, (float*)d_out);
}

// Round 2
// 356.259 us; speedup vs baseline: 1.0606x; 1.0606x over previous
//
#include <hip/hip_runtime.h>

// DeTPP loss: L=2048, B=64, K=4, C=128, I=512 selected positions per batch.
#define LL 2048
#define BB 64
#define KT 4
#define CC 128
#define II 512
#define NPOS (II * BB)   // 32768

// One WAVE per (i,b) position. No LDS, no barriers.
// 256 threads/block = 4 waves/block, 8192 blocks.
__global__ __launch_bounds__(256) void detpp_main(
    const float* __restrict__ in_time,        // (L, B)
    const float* __restrict__ in_amount,      // (L, B)
    const int*   __restrict__ in_mcc,         // (L, B)
    const float* __restrict__ out_time,       // (L, B, K)
    const float* __restrict__ out_amount,     // (L, B, K)
    const float* __restrict__ out_logits,     // (L, B, K, C)
    const float* __restrict__ presence,       // (L, B, K)
    const int*   __restrict__ indices,        // (I, B) flat = i*B+b
    const int*   __restrict__ subset_lengths, // (B,)
    float* __restrict__ partials)             // (NPOS,)
{
    const int lane = threadIdx.x & 63;
    const int wv   = threadIdx.x >> 6;
    const int p    = (blockIdx.x << 2) | wv;   // position index = i*B + b
    const int i    = p >> 6;
    const int b    = p & 63;

    if (i >= subset_lengths[b]) {
        if (lane == 0) partials[p] = 0.0f;
        return;                                 // wave-level exit, no barriers used
    }

    const int idx = indices[p];
    const size_t obase = ((size_t)idx * BB + b) * KT;      // base into (L,B,K)
    const float* __restrict__ lrow = out_logits + obase * CC;  // row k at +k*CC

    // ---- issue ALL loads up front (disjoint lane groups, fully parallel) ----
    float tval = 0.0f, aval = 0.0f, otv = 0.0f, oav = 0.0f, psv = 0.0f;
    int   cval = 0;
    if (lane < 5)                      tval = in_time  [(((idx + lane)      & (LL - 1)) << 6) + b];
    else if (lane >= 8  && lane < 13)  aval = in_amount[(((idx + lane - 8)  & (LL - 1)) << 6) + b];
    else if (lane >= 16 && lane < 21)  cval = in_mcc   [(((idx + lane - 16) & (LL - 1)) << 6) + b];
    else if (lane >= 24 && lane < 28)  otv = out_time  [obase + lane - 24];
    else if (lane >= 32 && lane < 36)  oav = out_amount[obase + lane - 32];
    else if (lane >= 40 && lane < 44)  psv = presence  [obase + lane - 40];

    // 4 logits rows, float2 per lane (512 B per row per wave, coalesced)
    const float2* l2 = reinterpret_cast<const float2*>(lrow) + lane;
    const float2 v0 = l2[0 * (CC / 2)];
    const float2 v1 = l2[1 * (CC / 2)];
    const float2 v2 = l2[2 * (CC / 2)];
    const float2 v3 = l2[3 * (CC / 2)];

    // ---- 4 × logsumexp over C=128 via 64-lane butterflies ----
#define LSE(vx, out)                                                      \
    {                                                                     \
        float mx = fmaxf(vx.x, vx.y);                                     \
        _Pragma("unroll")                                                 \
        for (int m = 32; m >= 1; m >>= 1) mx = fmaxf(mx, __shfl_xor(mx, m)); \
        float se = __expf(vx.x - mx) + __expf(vx.y - mx);                 \
        _Pragma("unroll")                                                 \
        for (int m = 32; m >= 1; m >>= 1) se += __shfl_xor(se, m);        \
        out = mx + logf(se);                                              \
    }
    float lse0, lse1, lse2, lse3;
    LSE(v0, lse0) LSE(v1, lse1) LSE(v2, lse2) LSE(v3, lse3)
#undef LSE

    // ---- lanes 0..15: cost[k][t], k = lane>>2, t = lane&3 ----
    const int k = lane >> 2;
    const int t = lane & 3;
    const int ct = __shfl(cval, 16 + 1 + t);          // true class cw[t+1]
    float ol = 0.0f;
    if (lane < 16) ol = lrow[k * CC + ct];            // L1-hot (row just read)
    const float lsek = (k == 0) ? lse0 : (k == 1) ? lse1 : (k == 2) ? lse2 : lse3;
    const float tw0  = __shfl(tval, 0);
    const float twt1 = __shfl(tval, 1 + t);
    const float awt1 = __shfl(aval, 9 + t);
    const float ot_k = __shfl(otv, 24 + k);
    const float oa_k = __shfl(oav, 32 + k);
    const float ps_k = __shfl(psv, 40 + k);
    const float cmy = (lsek - ol)                      // CE at true class
                    + fabsf(ot_k - (twt1 - tw0))       // time L1
                    + fabsf(oa_k - awt1)               // amount L1
                    - ps_k;                            // presence

    // broadcast the 16 cost entries to all lanes (named regs, static indices)
    const float c0  = __shfl(cmy, 0),  c1  = __shfl(cmy, 1),  c2  = __shfl(cmy, 2),  c3  = __shfl(cmy, 3);
    const float c4  = __shfl(cmy, 4),  c5  = __shfl(cmy, 5),  c6  = __shfl(cmy, 6),  c7  = __shfl(cmy, 7);
    const float c8  = __shfl(cmy, 8),  c9  = __shfl(cmy, 9),  c10 = __shfl(cmy, 10), c11 = __shfl(cmy, 11);
    const float c12 = __shfl(cmy, 12), c13 = __shfl(cmy, 13), c14 = __shfl(cmy, 14), c15 = __shfl(cmy, 15);

    // exact assignment: min over 24 permutations (all static indices)
    float best = c0 + c5 + c10 + c15;                         // 0123
    best = fminf(best, c0 + c5 + c11 + c14);                  // 0132
    best = fminf(best, c0 + c6 + c9  + c15);                  // 0213
    best = fminf(best, c0 + c6 + c11 + c13);                  // 0231
    best = fminf(best, c0 + c7 + c9  + c14);                  // 0312
    best = fminf(best, c0 + c7 + c10 + c13);                  // 0321
    best = fminf(best, c1 + c4 + c10 + c15);                  // 1023
    best = fminf(best, c1 + c4 + c11 + c14);                  // 1032
    best = fminf(best, c1 + c6 + c8  + c15);                  // 1203
    best = fminf(best, c1 + c6 + c11 + c12);                  // 1230
    best = fminf(best, c1 + c7 + c8  + c14);                  // 1302
    best = fminf(best, c1 + c7 + c10 + c12);                  // 1320
    best = fminf(best, c2 + c4 + c9  + c15);                  // 2013
    best = fminf(best, c2 + c4 + c11 + c13);                  // 2031
    best = fminf(best, c2 + c5 + c8  + c15);                  // 2103
    best = fminf(best, c2 + c5 + c11 + c12);                  // 2130
    best = fminf(best, c2 + c7 + c8  + c13);                  // 2301
    best = fminf(best, c2 + c7 + c9  + c12);                  // 2310
    best = fminf(best, c3 + c4 + c9  + c14);                  // 3012
    best = fminf(best, c3 + c4 + c10 + c13);                  // 3021
    best = fminf(best, c3 + c5 + c8  + c14);                  // 3102
    best = fminf(best, c3 + c5 + c10 + c12);                  // 3120
    best = fminf(best, c3 + c6 + c8  + c13);                  // 3201
    best = fminf(best, c3 + c6 + c9  + c12);                  // 3210

    // leftover: sum_k softplus(presence[k])  (= -log_sigmoid(-x))
    float leftover = 0.0f;
#pragma unroll
    for (int kk = 0; kk < KT; kk++) {
        const float x = __shfl(psv, 40 + kk);
        leftover += fmaxf(x, 0.0f) + log1pf(__expf(-fabsf(x)));
    }

    if (lane == 0) partials[p] = best + leftover;
}

__global__ __launch_bounds__(1024) void detpp_finish(
    const float* __restrict__ partials,
    const int*   __restrict__ subset_lengths,
    float* __restrict__ out)
{
    const int tid = threadIdx.x;
    float s = 0.0f;
#pragma unroll 8
    for (int j = tid; j < NPOS; j += 1024) s += partials[j];
#pragma unroll
    for (int m = 32; m >= 1; m >>= 1) s += __shfl_xor(s, m);

    __shared__ float red[16];
    const int wave = tid >> 6;
    const int lane = tid & 63;
    if (lane == 0) red[wave] = s;
    __syncthreads();

    if (tid == 0) {
        float tot = 0.0f;
#pragma unroll
        for (int w = 0; w < 16; w++) tot += red[w];
        int V = 0;
        for (int bb = 0; bb < BB; bb++) V += subset_lengths[bb];
        out[0] = tot / (float)V;
    }
}

extern "C" void kernel_launch(void* const* d_in, const int* in_sizes, int n_in,
                              void* d_out, int out_size, void* d_ws, size_t ws_size,
                              hipStream_t stream) {
    const float* in_time        = (const float*)d_in[0];
    const float* in_amount      = (const float*)d_in[1];
    const int*   in_mcc         = (const int*)  d_in[2];
    const float* out_time       = (const float*)d_in[3];
    const float* out_amount     = (const float*)d_in[4];
    const float* out_logits     = (const float*)d_in[5];
    const float* presence       = (const float*)d_in[6];
    // d_in[7] = lengths (unused; indices/subset_lengths already encode validity)
    const int*   indices        = (const int*)  d_in[8];
    const int*   subset_lengths = (const int*)  d_in[9];

    float* partials = (float*)d_ws;   // NPOS floats = 128 KB

    detpp_main<<<NPOS / 4, 256, 0, stream>>>(
        in_time, in_amount, in_mcc, out_time, out_amount, out_logits,
        presence, indices, subset_lengths, partials);

    detpp_finish<<<1, 1024, 0, stream>>>(partials, subset_lengths, (float*)d_out);
}